// Round 4
// baseline (218.124 us; speedup 1.0000x reference)
//
#include <hip/hip_runtime.h>

typedef unsigned short ushort_t;
typedef __bf16 bf16x8 __attribute__((ext_vector_type(8)));
typedef float f32x4 __attribute__((ext_vector_type(4)));
typedef const __attribute__((address_space(1))) void* gas1_t;
typedef __attribute__((address_space(3))) void* las3_t;

#define BB 2
#define LL 4096
#define DIMM 512
#define TOK (BB*LL)      // 8192
#define NCH 512          // BH*N chunks
#define MAX_LR_C 0.01f
#define EPS_C 1e-6f

__device__ __forceinline__ float sigmoidf_(float x){ return 1.0f/(1.0f + __expf(-x)); }
__device__ __forceinline__ ushort_t f2bf(float f){
    unsigned u = __builtin_bit_cast(unsigned, f);
    unsigned r = u + 0x7FFFu + ((u>>16)&1u);
    return (ushort_t)(r>>16);
}
__device__ __forceinline__ float bf2f(ushort_t h){
    unsigned u = ((unsigned)h)<<16; return __builtin_bit_cast(float, u);
}

// swizzled LDS offsets (element units, bf16): <=2-way bank aliasing (free, m136)
__device__ __forceinline__ int sw64x128(int t, int d){
    return (t<<7) | ((((d>>3) ^ (t&15))<<3) | (d&7));
}
__device__ __forceinline__ int sw128x64(int x, int t){
    return (x<<6) | ((((t>>3) ^ (x&7))<<3) | (t&7));
}

// ---------------------------------------------------------------------------
// Weight conversion/transpose to bf16 + d_out empty-prefix fill + zero accums.
// ---------------------------------------------------------------------------
__global__ __launch_bounds__(256) void k_convert(
    const float* __restrict__ w_kv, const float* __restrict__ w_q,
    const float* __restrict__ w_comb, const float* __restrict__ w0,
    const float* __restrict__ w1, const float* __restrict__ empty,
    ushort_t* __restrict__ w_kvT, ushort_t* __restrict__ w_qT,
    ushort_t* __restrict__ w_combT, ushort_t* __restrict__ w0T_b,
    ushort_t* __restrict__ w1T_b, ushort_t* __restrict__ w1row_b,
    float* __restrict__ w0T_f, float* __restrict__ w1T_f,
    float* __restrict__ outp, float* __restrict__ amraw, float* __restrict__ dcraw)
{
    int i = blockIdx.x*256 + threadIdx.x;
    if (i < 524288){ int n=i>>9, k=i&511; w_kvT[i] = f2bf(w_kv[k*1024+n]); return; }
    i -= 524288;
    if (i < 262144){ int n=i>>9, k=i&511; w_qT[i] = f2bf(w_q[k*512+n]); return; }
    i -= 262144;
    if (i < 262144){ int n=i>>9, k=i&511; w_combT[i] = f2bf(w_comb[k*512+n]); return; }
    i -= 262144;
    if (i < 16384){ int n=i>>7, k=i&127; float v=w0[k*128+n]; w0T_b[i]=f2bf(v); w0T_f[i]=v; return; }
    i -= 16384;
    if (i < 16384){ int n=i>>7, k=i&127; float v=w1[k*128+n]; w1T_b[i]=f2bf(v); w1T_f[i]=v; return; }
    i -= 16384;
    if (i < 16384){ w1row_b[i] = f2bf(w1[i]); return; }
    i -= 16384;
    if (i < BB*63*DIMM){
        int b = i/(63*DIMM); int r = i%(63*DIMM);
        int t = r>>9, d = r&511;
        outp[((size_t)b*LL + t)*DIMM + d] = empty[d];
        return;
    }
    i -= BB*63*DIMM;
    if (i < 1024){ if (i<512) amraw[i]=0.f; else dcraw[i-512]=0.f; }
}

// ---------------------------------------------------------------------------
// Fused RMSNorm + per-token lr/gate + chunk-stat partials.
// One block per half-chunk (32 tokens); atomicAdd raw mom/dec logits
// (exactly 2 addends per slot -> order-invariant). Sigmoid applied in k_scan2.
// ---------------------------------------------------------------------------
__global__ __launch_bounds__(256) void k_prep(
    const float* __restrict__ seq, const float* __restrict__ sscale,
    const float* __restrict__ rscale, const float* __restrict__ w_ada,
    const float* __restrict__ w_mom, const float* __restrict__ w_dec,
    const float* __restrict__ w_gate, ushort_t* __restrict__ s,
    ushort_t* __restrict__ rc, float* __restrict__ lr, float* __restrict__ gate,
    float* __restrict__ amraw, float* __restrict__ dcraw)
{
    int c2 = blockIdx.x;
    int b = c2>>7, n = (c2>>1)&63, half = c2&1;
    int wave = threadIdx.x>>6, lane = threadIdx.x&63;
    float macc[8] = {0,0,0,0,0,0,0,0};
    #pragma unroll 1
    for (int tt=0; tt<8; tt++){
        int t = n*64 + half*32 + wave*8 + tt;
        int tok = b*LL + t;
        const float* x = seq + (size_t)tok*DIMM;
        float v[8]; float ss = 0.f;
        #pragma unroll
        for (int j=0;j<8;j++){ v[j] = x[lane + 64*j]; ss += v[j]*v[j]; }
        #pragma unroll
        for (int m=1;m<64;m<<=1) ss += __shfl_xor(ss, m, 64);
        float rstd = rsqrtf(ss * (1.0f/DIMM) + EPS_C);
        float pa[4] = {0,0,0,0}, pg[4] = {0,0,0,0};
        ushort_t se[8], re[8];
        #pragma unroll
        for (int j=0;j<8;j++){
            int d = lane + 64*j;
            float nv = v[j]*rstd;
            float sv = nv * sscale[d];
            float rv = nv * rscale[d];
            macc[j] += sv;
            se[j] = f2bf(sv); re[j] = f2bf(rv);
            #pragma unroll
            for (int hh=0;hh<4;hh++){
                pa[hh] += sv*w_ada[d*4+hh];
                pg[hh] += rv*w_gate[d*4+hh];
            }
        }
        ushort_t* srow = s + (size_t)tok*DIMM;
        #pragma unroll
        for (int j=0;j<8;j++) srow[lane+64*j] = se[j];
        if (t >= 63){
            ushort_t* rrow = rc + ((size_t)b*LL + (t-63))*DIMM;
            #pragma unroll
            for (int j=0;j<8;j++) rrow[lane+64*j] = re[j];
        } else {
            ushort_t* rrow = rc + ((size_t)b*LL + (LL-63+t))*DIMM;
            #pragma unroll
            for (int j=0;j<8;j++) rrow[lane+64*j] = 0;
        }
        #pragma unroll
        for (int hh=0;hh<4;hh++){
            #pragma unroll
            for (int m=1;m<64;m<<=1){
                pa[hh] += __shfl_xor(pa[hh], m, 64);
                pg[hh] += __shfl_xor(pg[hh], m, 64);
            }
        }
        if (lane < 4){
            int hh = lane;
            lr[((size_t)(b*4+hh))*LL + t] = sigmoidf_(pa[hh]) * MAX_LR_C;
            if (t >= 63) gate[((size_t)b*LL + (t-63))*4 + hh] = sigmoidf_(pg[hh]);
            else         gate[((size_t)b*LL + (LL-63+t))*4 + hh] = 0.5f;
        }
    }
    // chunk-mean partial projections
    float pmh[4]={0,0,0,0}, pdh[4]={0,0,0,0};
    #pragma unroll
    for (int j=0;j<8;j++){
        int d = lane + 64*j;
        #pragma unroll
        for (int hh=0;hh<4;hh++){
            pmh[hh] += macc[j]*w_mom[d*4+hh];
            pdh[hh] += macc[j]*w_dec[d*4+hh];
        }
    }
    #pragma unroll
    for (int hh=0;hh<4;hh++){
        #pragma unroll
        for (int m=1;m<64;m<<=1){
            pmh[hh]+=__shfl_xor(pmh[hh],m,64);
            pdh[hh]+=__shfl_xor(pdh[hh],m,64);
        }
    }
    __shared__ float lds[4][8];
    if (lane==0){
        #pragma unroll
        for (int hh=0;hh<4;hh++){ lds[wave][hh]=pmh[hh]; lds[wave][4+hh]=pdh[hh]; }
    }
    __syncthreads();
    if (threadIdx.x < 8){
        float tot = lds[0][threadIdx.x]+lds[1][threadIdx.x]+lds[2][threadIdx.x]+lds[3][threadIdx.x];
        int hh = threadIdx.x & 3;
        float* dst = (threadIdx.x < 4) ? amraw : dcraw;
        atomicAdd(&dst[(b*4+hh)*64 + n], tot * (1.0f/64.0f));
    }
}

// ---------------------------------------------------------------------------
// bf16 MFMA GEMM (m97 structure): 128x128 tile, BK=32, global_load_lds staging.
// MODE 0 kv:   O1=keys[t][d] hm, O2=keysT[d][t] chunk, O3=vals[t][d] hm
// MODE 5 comb: FO=d_out fp32 with +63 shift
// ---------------------------------------------------------------------------
template<int MODE>
__global__ __launch_bounds__(256) void k_mm(
    const ushort_t* __restrict__ A, const ushort_t* __restrict__ BT,
    ushort_t* __restrict__ O1, ushort_t* __restrict__ O2, ushort_t* __restrict__ O3,
    float* __restrict__ FO, int M, int N, int K)
{
    __shared__ ushort_t As[128*32];
    __shared__ ushort_t Bs[128*32];
    int tid = threadIdx.x;
    int w = tid>>6, l = tid&63;
    int row0 = blockIdx.y*128, col0 = blockIdx.x*128;
    int wm = (w>>1)*64, wn = (w&1)*64;
    int lr16 = l&15, q = l>>4;
    f32x4 acc[4][4] = {};
    int arow = l>>2;
    int akof = (l&3)<<3;
    const size_t rA0 = (size_t)(row0 + w*16 + arow)*(size_t)K + akof;
    const size_t rA1 = rA0 + (size_t)64*K;
    const size_t rB0 = (size_t)(col0 + w*16 + arow)*(size_t)K + akof;
    const size_t rB1 = rB0 + (size_t)64*K;
    for (int k0=0; k0<K; k0+=32){
        __builtin_amdgcn_global_load_lds((gas1_t)(const void*)(A + rA0 + k0),
                                         (las3_t)(void*)(As + w*512), 16, 0, 0);
        __builtin_amdgcn_global_load_lds((gas1_t)(const void*)(A + rA1 + k0),
                                         (las3_t)(void*)(As + 2048 + w*512), 16, 0, 0);
        __builtin_amdgcn_global_load_lds((gas1_t)(const void*)(BT + rB0 + k0),
                                         (las3_t)(void*)(Bs + w*512), 16, 0, 0);
        __builtin_amdgcn_global_load_lds((gas1_t)(const void*)(BT + rB1 + k0),
                                         (las3_t)(void*)(Bs + 2048 + w*512), 16, 0, 0);
        __syncthreads();
        bf16x8 af[4], bfv[4];
        #pragma unroll
        for (int i=0;i<4;i++){
            af[i]  = *(const bf16x8*)&As[(wm + i*16 + lr16)*32 + q*8];
            bfv[i] = *(const bf16x8*)&Bs[(wn + i*16 + lr16)*32 + q*8];
        }
        #pragma unroll
        for (int i=0;i<4;i++)
            #pragma unroll
            for (int j=0;j<4;j++)
                acc[i][j] = __builtin_amdgcn_mfma_f32_16x16x32_bf16(af[i], bfv[j], acc[i][j], 0,0,0);
        __syncthreads();
    }
    #pragma unroll
    for (int i=0;i<4;i++){
        int trb = row0 + wm + i*16 + q*4;
        #pragma unroll
        for (int j=0;j<4;j++){
            int tcol = col0 + wn + j*16 + lr16;
            f32x4 v = acc[i][j];
            if constexpr (MODE==0){
                int bb = trb>>12, l0 = trb&4095;
                int hh = (tcol>>7)&3, dd = tcol&127;
                size_t hm = ((size_t)(bb*4+hh)*LL + l0)*128 + dd;
                ushort_t e0=f2bf(v[0]), e1=f2bf(v[1]), e2=f2bf(v[2]), e3=f2bf(v[3]);
                if (tcol < 512){
                    O1[hm]=e0; O1[hm+128]=e1; O1[hm+256]=e2; O1[hm+384]=e3;
                    int ch = (bb*4+hh)*64 + (l0>>6);
                    ushort4 pk; pk.x=e0; pk.y=e1; pk.z=e2; pk.w=e3;
                    *(ushort4*)&O2[(size_t)ch*8192 + dd*64 + (l0&63)] = pk;
                } else {
                    O3[hm]=e0; O3[hm+128]=e1; O3[hm+256]=e2; O3[hm+384]=e3;
                }
            } else { // 5
                int bb = trb>>12;
                #pragma unroll
                for (int r=0;r<4;r++){
                    int t = (trb&4095)+r;
                    if (t < LL-63)
                        FO[((size_t)bb*LL + t + 63)*DIMM + tcol] = v[r];
                }
            }
        }
    }
}

// ---------------------------------------------------------------------------
// Fused per-chunk store pipeline. One block/chunk, 80KB LDS, 7 barriers.
// sK: keys -> siluHT | sV: vals -> dP -> dHT | sH: siluH -> dPT | sW: weights/keysT
// ---------------------------------------------------------------------------
__global__ __launch_bounds__(256,2) void k_fused(
    const ushort_t* __restrict__ keys, const ushort_t* __restrict__ vals,
    const ushort_t* __restrict__ keysT, const ushort_t* __restrict__ w0T,
    const ushort_t* __restrict__ w1T, const ushort_t* __restrict__ w1row,
    const float* __restrict__ lr, ushort_t* __restrict__ G0,
    ushort_t* __restrict__ G1)
{
    __shared__ ushort_t sK[8192];
    __shared__ ushort_t sV[8192];
    __shared__ ushort_t sH[8192];
    __shared__ ushort_t sW[16384];
    int ch = blockIdx.x;
    int tid = threadIdx.x;
    int w = tid>>6, l = tid&63, lr16 = l&15, q = l>>4;
    const size_t R0 = (size_t)ch*64;

    auto load_w = [&](const ushort_t* Wg){
        #pragma unroll
        for (int u=0; u<8; u++){
            int flat = u*2048 + tid*8;
            int r_ = flat>>7, c = flat&127;
            int off = (r_<<7) | ((((c>>3) ^ (r_&15))<<3));
            *(uint4*)&sW[off] = *(const uint4*)&Wg[flat];
        }
    };

    // stage keys, vals into swizzled [64][128]; full w0T
    #pragma unroll
    for (int it=0; it<4; it++){
        int flat = it*2048 + tid*8;
        int t = flat>>7, d = flat&127;
        int off = (t<<7) | ((((d>>3) ^ (t&15))<<3));
        *(uint4*)&sK[off] = *(const uint4*)&keys[(R0<<7) + flat];
        *(uint4*)&sV[off] = *(const uint4*)&vals[(R0<<7) + flat];
    }
    load_w(w0T);
    __syncthreads();

    // ---- Phase A: HT[i][t] = sum_a w0T[i][a] keys[t][a]
    f32x4 acc[2][4] = {};
    #pragma unroll
    for (int s=0; s<4; s++){
        bf16x8 af[2], bv[4];
        #pragma unroll
        for (int mi=0;mi<2;mi++){
            int r_ = w*32 + mi*16 + lr16;
            af[mi] = *(const bf16x8*)&sW[(r_<<7) | ((((s*4+q) ^ (r_&15))<<3))];
        }
        #pragma unroll
        for (int nj=0;nj<4;nj++){
            int t = nj*16 + lr16;
            bv[nj] = *(const bf16x8*)&sK[(t<<7) | ((((s*4+q) ^ (t&15))<<3))];
        }
        #pragma unroll
        for (int mi=0;mi<2;mi++)
            #pragma unroll
            for (int nj=0;nj<4;nj++)
                acc[mi][nj] = __builtin_amdgcn_mfma_f32_16x16x32_bf16(af[mi], bv[nj], acc[mi][nj], 0,0,0);
    }
    __syncthreads();
    // A-epilogue: siluH -> sH [t][i], siluHT -> sK [i][t], silu' -> regs; w1T -> sW
    f32x4 sp[2][4];
    #pragma unroll
    for (int mi=0;mi<2;mi++){
        int i0 = w*32 + mi*16 + q*4;
        #pragma unroll
        for (int nj=0;nj<4;nj++){
            int t = nj*16 + lr16;
            ushort_t e[4];
            #pragma unroll
            for (int r=0;r<4;r++){
                float hv = acc[mi][nj][r];
                float sg = sigmoidf_(hv);
                sp[mi][nj][r] = sg*(1.f + hv*(1.f - sg));
                e[r] = f2bf(hv*sg);
                sK[sw128x64(i0+r, t)] = e[r];
            }
            ushort4 pk; pk.x=e[0]; pk.y=e[1]; pk.z=e[2]; pk.w=e[3];
            *(ushort4*)&sH[(t<<7) | ((((i0>>3) ^ (t&15))<<3) | (i0&7))] = pk;
        }
    }
    load_w(w1T);
    __syncthreads();

    // ---- Phase B: PT[j][t] = sum_i w1T[j][i] siluH[t][i]
    float lrw[4];
    #pragma unroll
    for (int nj=0;nj<4;nj++) lrw[nj] = lr[R0 + nj*16 + lr16];
    f32x4 accb[2][4] = {};
    #pragma unroll
    for (int s=0; s<4; s++){
        bf16x8 af[2], bv[4];
        #pragma unroll
        for (int mi=0;mi<2;mi++){
            int r_ = w*32 + mi*16 + lr16;
            af[mi] = *(const bf16x8*)&sW[(r_<<7) | ((((s*4+q) ^ (r_&15))<<3))];
        }
        #pragma unroll
        for (int nj=0;nj<4;nj++){
            int t = nj*16 + lr16;
            bv[nj] = *(const bf16x8*)&sH[(t<<7) | ((((s*4+q) ^ (t&15))<<3))];
        }
        #pragma unroll
        for (int mi=0;mi<2;mi++)
            #pragma unroll
            for (int nj=0;nj<4;nj++)
                accb[mi][nj] = __builtin_amdgcn_mfma_f32_16x16x32_bf16(af[mi], bv[nj], accb[mi][nj], 0,0,0);
    }
    __syncthreads();
    // B-epilogue: dP -> sV (in place per-thread), dPT -> sH; w1row -> sW
    #pragma unroll
    for (int mi=0;mi<2;mi++){
        int j0 = w*32 + mi*16 + q*4;
        #pragma unroll
        for (int nj=0;nj<4;nj++){
            int t = nj*16 + lr16;
            int voff = (t<<7) | ((((j0>>3) ^ (t&15))<<3) | (j0&7));
            ushort4 vv = *(ushort4*)&sV[voff];
            float vf[4] = {bf2f(vv.x), bf2f(vv.y), bf2f(vv.z), bf2f(vv.w)};
            ushort_t e[4];
            #pragma unroll
            for (int r=0;r<4;r++){
                float dp = 0.015625f * lrw[nj] * (accb[mi][nj][r] - vf[r]);
                e[r] = f2bf(dp);
                sH[sw128x64(j0+r, t)] = e[r];
            }
            ushort4 pk; pk.x=e[0]; pk.y=e[1]; pk.z=e[2]; pk.w=e[3];
            *(ushort4*)&sV[voff] = pk;
        }
    }
    load_w(w1row);
    __syncthreads();

    // ---- Phase C: g1T[j][i] = sum_t dPT[j][t] siluHT[i][t]
    {
        f32x4 accc[2][8] = {};
        #pragma unroll
        for (int k0=0;k0<64;k0+=32){
            bf16x8 af[2], bv[8];
            #pragma unroll
            for (int mi=0;mi<2;mi++){
                int j_ = w*32 + mi*16 + lr16;
                af[mi] = *(const bf16x8*)&sH[(j_<<6) | (((((k0>>3)+q) ^ (j_&7))<<3))];
            }
            #pragma unroll
            for (int nj=0;nj<8;nj++){
                int i_ = nj*16 + lr16;
                bv[nj] = *(const bf16x8*)&sK[(i_<<6) | (((((k0>>3)+q) ^ (i_&7))<<3))];
            }
            #pragma unroll
            for (int mi=0;mi<2;mi++)
                #pragma unroll
                for (int nj=0;nj<8;nj++)
                    accc[mi][nj] = __builtin_amdgcn_mfma_f32_16x16x32_bf16(af[mi], bv[nj], accc[mi][nj], 0,0,0);
        }
        #pragma unroll
        for (int mi=0;mi<2;mi++){
            int j0 = w*32 + mi*16 + q*4;
            #pragma unroll
            for (int nj=0;nj<8;nj++){
                int i_ = nj*16 + lr16;
                #pragma unroll
                for (int r=0;r<4;r++)
                    G1[(size_t)ch*16384 + (size_t)(j0+r)*128 + i_] = f2bf(accc[mi][nj][r]);
            }
        }
    }

    // ---- Phase D: dHT[i][t] = (sum_j w1[i][j] dP[t][j]) * sp[i][t]
    f32x4 accd[2][4] = {};
    #pragma unroll
    for (int s=0; s<4; s++){
        bf16x8 af[2], bv[4];
        #pragma unroll
        for (int mi=0;mi<2;mi++){
            int r_ = w*32 + mi*16 + lr16;
            af[mi] = *(const bf16x8*)&sW[(r_<<7) | ((((s*4+q) ^ (r_&15))<<3))];
        }
        #pragma unroll
        for (int nj=0;nj<4;nj++){
            int t = nj*16 + lr16;
            bv[nj] = *(const bf16x8*)&sV[(t<<7) | ((((s*4+q) ^ (t&15))<<3))];
        }
        #pragma unroll
        for (int mi=0;mi<2;mi++)
            #pragma unroll
            for (int nj=0;nj<4;nj++)
                accd[mi][nj] = __builtin_amdgcn_mfma_f32_16x16x32_bf16(af[mi], bv[nj], accd[mi][nj], 0,0,0);
    }
    __syncthreads();
    // D-epilogue: dHT -> sV; keysT -> sW
    #pragma unroll
    for (int mi=0;mi<2;mi++){
        int i0 = w*32 + mi*16 + q*4;
        #pragma unroll
        for (int nj=0;nj<4;nj++){
            int t = nj*16 + lr16;
            #pragma unroll
            for (int r=0;r<4;r++)
                sV[sw128x64(i0+r, t)] = f2bf(accd[mi][nj][r] * sp[mi][nj][r]);
        }
    }
    #pragma unroll
    for (int it=0; it<4; it++){
        int flat = it*2048 + tid*8;
        int x = flat>>6, t = flat&63;
        int off = (x<<6) | ((((t>>3) ^ (x&7))<<3));
        *(uint4*)&sW[off] = *(const uint4*)&keysT[(size_t)ch*8192 + flat];
    }
    __syncthreads();

    // ---- Phase E: g0T[i][a] = sum_t dHT[i][t] keysT[a][t]
    {
        f32x4 acce[2][8] = {};
        #pragma unroll
        for (int k0=0;k0<64;k0+=32){
            bf16x8 af[2], bv[8];
            #pragma unroll
            for (int mi=0;mi<2;mi++){
                int i_ = w*32 + mi*16 + lr16;
                af[mi] = *(const bf16x8*)&sV[(i_<<6) | (((((k0>>3)+q) ^ (i_&7))<<3))];
            }
            #pragma unroll
            for (int nj=0;nj<8;nj++){
                int a_ = nj*16 + lr16;
                bv[nj] = *(const bf16x8*)&sW[(a_<<6) | (((((k0>>3)+q) ^ (a_&7))<<3))];
            }
            #pragma unroll
            for (int mi=0;mi<2;mi++)
                #pragma unroll
                for (int nj=0;nj<8;nj++)
                    acce[mi][nj] = __builtin_amdgcn_mfma_f32_16x16x32_bf16(af[mi], bv[nj], acce[mi][nj], 0,0,0);
        }
        #pragma unroll
        for (int mi=0;mi<2;mi++){
            int i0 = w*32 + mi*16 + q*4;
            #pragma unroll
            for (int nj=0;nj<8;nj++){
                int a_ = nj*16 + lr16;
                #pragma unroll
                for (int r=0;r<4;r++)
                    G0[(size_t)ch*16384 + (size_t)(i0+r)*128 + a_] = f2bf(acce[mi][nj][r]);
            }
        }
    }
}

// ---------------------------------------------------------------------------
// Both scans, vectorized x4 with next-n prefetch; sigmoid of raw logits inline.
// ---------------------------------------------------------------------------
__global__ __launch_bounds__(256) void k_scan2(
    const ushort_t* __restrict__ G0, const ushort_t* __restrict__ G1,
    const float* __restrict__ w0T_f, const float* __restrict__ w1T_f,
    const float* __restrict__ amraw, const float* __restrict__ dcraw,
    ushort_t* __restrict__ wt0T, ushort_t* __restrict__ wt1T)
{
    int half = blockIdx.x >> 7;
    int base = ((blockIdx.x & 127)*256 + threadIdx.x)*4;
    const ushort_t* G = half ? G1 : G0;
    const float* winit = half ? w1T_f : w0T_f;
    ushort_t* wt = half ? wt1T : wt0T;
    int bh = base >> 14;
    int rem = base & 16383;
    float4 wv = *(const float4*)&winit[rem];
    float mom[4] = {0,0,0,0}, upd[4] = {0,0,0,0};
    size_t idx = ((size_t)(bh*64))*16384 + rem;
    ushort4 g = *(const ushort4*)&G[idx];
    for (int n=0;n<64;n++){
        ushort4 gn = (n<63) ? *(const ushort4*)&G[idx + 16384] : g;
        float a = sigmoidf_(amraw[bh*64+n]);
        float d1 = 1.f - sigmoidf_(dcraw[bh*64+n]);
        float su[4] = {-bf2f(g.x), -bf2f(g.y), -bf2f(g.z), -bf2f(g.w)};
        #pragma unroll
        for (int e=0;e<4;e++){
            mom[e] = (n==0) ? su[e] : a*mom[e] + su[e];
            upd[e] = (n==0) ? mom[e] : d1*upd[e] + mom[e];
        }
        ushort4 o;
        o.x = f2bf(wv.x + upd[0]); o.y = f2bf(wv.y + upd[1]);
        o.z = f2bf(wv.z + upd[2]); o.w = f2bf(wv.w + upd[3]);
        *(ushort4*)&wt[idx] = o;
        g = gn;
        idx += 16384;
    }
}

// ---------------------------------------------------------------------------
// Retrieve with fused Q-GEMM: Q = rc @ w_q (head slice), then
// out = silu(Q @ w0t) @ w1t, MH-RMSNorm * (gamma+1) * gate.
// ---------------------------------------------------------------------------
__global__ __launch_bounds__(256) void k_retr(
    const ushort_t* __restrict__ rc, const ushort_t* __restrict__ w_qT,
    const ushort_t* __restrict__ W0t, const ushort_t* __restrict__ W1t,
    const float* __restrict__ gamma, const float* __restrict__ gate,
    ushort_t* __restrict__ out_pre)
{
    int chunk = blockIdx.x;
    int bh = chunk>>6, n = chunk&63, b = bh>>2, h = bh&3;
    __shared__ ushort_t Qs[64*136];
    __shared__ ushort_t Ws[128*136];
    __shared__ ushort_t O1s[64*136];
    int tid = threadIdx.x;
    int w = tid>>6, l = tid&63, lr16 = l&15, q = l>>4;

    // ---- Q phase: qacc[t-tile w][qdim] over K=512 in 4 slices of 128
    f32x4 qacc[8] = {};
    for (int s4=0; s4<4; s4++){
        #pragma unroll
        for (int u=0;u<4;u++){
            int flat = u*2048 + tid*8;
            int row = flat>>7, c = flat&127;
            *(uint4*)&O1s[row*136+c] =
                *(const uint4*)&rc[((size_t)b*LL + n*64 + row)*DIMM + s4*128 + c];
        }
        #pragma unroll
        for (int u=0;u<8;u++){
            int flat = u*2048 + tid*8;
            int row = flat>>7, c = flat&127;
            *(uint4*)&Ws[row*136+c] =
                *(const uint4*)&w_qT[((size_t)(h*128+row))*DIMM + s4*128 + c];
        }
        __syncthreads();
        #pragma unroll
        for (int kk=0;kk<4;kk++){
            bf16x8 af = *(const bf16x8*)&O1s[(w*16+lr16)*136 + kk*32 + q*8];
            #pragma unroll
            for (int j=0;j<8;j++){
                bf16x8 bv = *(const bf16x8*)&Ws[(j*16+lr16)*136 + kk*32 + q*8];
                qacc[j] = __builtin_amdgcn_mfma_f32_16x16x32_bf16(af, bv, qacc[j], 0,0,0);
            }
        }
        __syncthreads();
    }
    // write Qs [t][qdim]; stage W0t
    #pragma unroll
    for (int j=0;j<8;j++)
        #pragma unroll
        for (int r=0;r<4;r++)
            Qs[(w*16+q*4+r)*136 + j*16+lr16] = f2bf(qacc[j][r]);
    const ushort_t* W0b = W0t + (size_t)chunk*16384;
    #pragma unroll
    for (int it=0; it<8; it++){
        int i = tid*8 + it*2048;
        int row=i>>7, c=i&127;
        *(uint4*)&Ws[row*136+c] = *(const uint4*)&W0b[i];
    }
    __syncthreads();

    // ---- hidden = Q @ w0t
    f32x4 acc[8] = {};
    #pragma unroll
    for (int k0=0;k0<128;k0+=32){
        bf16x8 af = *(const bf16x8*)&Qs[(w*16+lr16)*136 + k0 + q*8];
        #pragma unroll
        for (int j=0;j<8;j++){
            bf16x8 bv = *(const bf16x8*)&Ws[(j*16+lr16)*136 + k0 + q*8];
            acc[j] = __builtin_amdgcn_mfma_f32_16x16x32_bf16(af, bv, acc[j], 0,0,0);
        }
    }
    __syncthreads();
    #pragma unroll
    for (int j=0;j<8;j++){
        #pragma unroll
        for (int r=0;r<4;r++){
            float hv = acc[j][r];
            float sg = sigmoidf_(hv);
            O1s[(w*16+q*4+r)*136 + j*16+lr16] = f2bf(hv*sg);
        }
    }
    const ushort_t* W1b = W1t + (size_t)chunk*16384;
    #pragma unroll
    for (int it=0; it<8; it++){
        int i = tid*8 + it*2048;
        int row=i>>7, c=i&127;
        *(uint4*)&Ws[row*136+c] = *(const uint4*)&W1b[i];
    }
    __syncthreads();

    // ---- out = silu(hidden) @ w1t
    f32x4 acc2[8] = {};
    #pragma unroll
    for (int k0=0;k0<128;k0+=32){
        bf16x8 af = *(const bf16x8*)&O1s[(w*16+lr16)*136 + k0 + q*8];
        #pragma unroll
        for (int j=0;j<8;j++){
            bf16x8 bv = *(const bf16x8*)&Ws[(j*16+lr16)*136 + k0 + q*8];
            acc2[j] = __builtin_amdgcn_mfma_f32_16x16x32_bf16(af, bv, acc2[j], 0,0,0);
        }
    }
    float ssq[4] = {0,0,0,0};
    #pragma unroll
    for (int j=0;j<8;j++)
        #pragma unroll
        for (int r=0;r<4;r++) ssq[r] += acc2[j][r]*acc2[j][r];
    #pragma unroll
    for (int r=0;r<4;r++){
        ssq[r] += __shfl_xor(ssq[r], 1, 64);
        ssq[r] += __shfl_xor(ssq[r], 2, 64);
        ssq[r] += __shfl_xor(ssq[r], 4, 64);
        ssq[r] += __shfl_xor(ssq[r], 8, 64);
    }
    int tok0 = n*64 + w*16 + q*4;
    #pragma unroll
    for (int r=0;r<4;r++){
        float rstd = rsqrtf(ssq[r]*(1.0f/128.0f) + EPS_C);
        float gv = gate[((size_t)b*LL + tok0 + r)*4 + h];
        #pragma unroll
        for (int j=0;j<8;j++){
            int d = j*16 + lr16;
            float val = acc2[j][r]*rstd*(gamma[h*128+d]+1.0f)*gv;
            out_pre[((size_t)b*LL + tok0 + r)*DIMM + h*128 + d] = f2bf(val);
        }
    }
}

extern "C" void kernel_launch(void* const* d_in, const int* in_sizes, int n_in,
                              void* d_out, int out_size, void* d_ws, size_t ws_size,
                              hipStream_t stream)
{
    (void)in_sizes; (void)n_in; (void)out_size; (void)ws_size;
    const float* seq    = (const float*)d_in[0];
    const float* sscale = (const float*)d_in[1];
    const float* rscale = (const float*)d_in[2];
    const float* w_q    = (const float*)d_in[3];
    const float* w_kv   = (const float*)d_in[4];
    const float* w_ada  = (const float*)d_in[5];
    const float* w_mom  = (const float*)d_in[6];
    const float* w_dec  = (const float*)d_in[7];
    const float* w0     = (const float*)d_in[8];
    const float* w1     = (const float*)d_in[9];
    const float* gamma  = (const float*)d_in[10];
    const float* w_gate = (const float*)d_in[11];
    const float* w_comb = (const float*)d_in[12];
    const float* empty  = (const float*)d_in[13];
    float* out = (float*)d_out;
    char* wsb = (char*)d_ws;

    ushort_t* bufS  = (ushort_t*)(wsb + 0);          // s
    ushort_t* bufK  = (ushort_t*)(wsb + 8388608);    // keys -> out_pre
    ushort_t* bufV  = (ushort_t*)(wsb + 16777216);   // vals
    ushort_t* bufKT = (ushort_t*)(wsb + 25165824);   // keysT
    ushort_t* bufRC = (ushort_t*)(wsb + 33554432);   // rc (shifted)
    ushort_t* G0    = (ushort_t*)(wsb + 50331648);
    ushort_t* G1    = (ushort_t*)(wsb + 67108864);
    ushort_t* wt0T  = (ushort_t*)(wsb + 83886080);
    ushort_t* wt1T  = (ushort_t*)(wsb + 100663296);
    ushort_t* w_kvT   = (ushort_t*)(wsb + 117440512);
    ushort_t* w_qT    = (ushort_t*)(wsb + 118489088);
    ushort_t* w_combT = (ushort_t*)(wsb + 119013376);
    ushort_t* w0T_b   = (ushort_t*)(wsb + 119537664);
    ushort_t* w1T_b   = (ushort_t*)(wsb + 119570432);
    ushort_t* w1row_b = (ushort_t*)(wsb + 119603200);
    float* w0T_f = (float*)(wsb + 119635968);
    float* w1T_f = (float*)(wsb + 119701504);
    float* lrbuf = (float*)(wsb + 119767040);
    float* gtbuf = (float*)(wsb + 119898112);
    float* amraw = (float*)(wsb + 120029184);
    float* dcraw = (float*)(wsb + 120031232);

    k_convert<<<4544, 256, 0, stream>>>(w_kv, w_q, w_comb, w0, w1, empty,
        w_kvT, w_qT, w_combT, w0T_b, w1T_b, w1row_b, w0T_f, w1T_f,
        out, amraw, dcraw);
    k_prep<<<256, 256, 0, stream>>>(seq, sscale, rscale, w_ada, w_mom, w_dec,
        w_gate, bufS, bufRC, lrbuf, gtbuf, amraw, dcraw);
    // kv: keys(bufK) keysT(bufKT) vals(bufV)
    k_mm<0><<<dim3(8,64), 256, 0, stream>>>(bufS, w_kvT, bufK, bufKT, bufV,
        nullptr, 8192, 1024, 512);
    // fused store pipeline -> g0T(G0), g1T(G1)
    k_fused<<<NCH, 256, 0, stream>>>(bufK, bufV, bufKT, w0T_b, w1T_b, w1row_b,
        lrbuf, G0, G1);
    // both scans -> wt0T / wt1T (sigmoid of raw logits inline)
    k_scan2<<<256, 256, 0, stream>>>(G0, G1, w0T_f, w1T_f, amraw, dcraw,
        wt0T, wt1T);
    // retrieve (Q fused) -> out_pre (bufK)
    k_retr<<<NCH, 256, 0, stream>>>(bufRC, w_qT, wt0T, wt1T, gamma, gtbuf, bufK);
    // combine -> d_out (shifted); rows 0..62 already filled by k_convert
    k_mm<5><<<dim3(4,64), 256, 0, stream>>>(bufK, w_combT, nullptr, nullptr, nullptr,
        out, 8192, 512, 512);
}